// Round 15
// baseline (2339.455 us; speedup 1.0000x reference)
//
#include <hip/hip_runtime.h>
#include <hip/hip_bf16.h>

typedef __hip_bfloat16 bf16;

#define NN 100000
#define NE 1600000
#define DD 64
#define NL 3
#define NG 128
#define BN_EPS 1e-5f
#define SCAN_BLK 98  // ceil(NN / 1024)
#define TILE_ROWS 64
#define NT ((NN + TILE_ROWS - 1) / TILE_ROWS)  // 1563
#define GB_NODES 49
#define GB_BLOCKS ((NN + GB_NODES - 1) / GB_NODES)  // 2041
#define ECAP 1280    // staged padded edges per block (mean ~955, sd ~28)
#define CSW_CAP (NE + 7 * NN)  // padded CSR worst case

// ---------------- dtype detect (int64 vs int32) ----------------
__global__ __launch_bounds__(256) void detect_kernel(const int* __restrict__ ei,
                                                     const int* __restrict__ batch,
                                                     int* __restrict__ flags) {
    __shared__ int s_e, s_b;
    if (threadIdx.x == 0) { s_e = 0; s_b = 0; }
    __syncthreads();
    for (int i = threadIdx.x; i < 512; i += 256) {
        if (ei[2 * i + 1] != 0) atomicOr(&s_e, 1);
        if (batch[NN - 1024 + 2 * i + 1] != 0) atomicOr(&s_b, 1);
    }
    __syncthreads();
    if (threadIdx.x == 0) { flags[0] = s_e; flags[1] = s_b; }  // 1 = int32, 0 = int64
}

__device__ __forceinline__ int ld_src(const int* ei, int e, int is32) {
    return is32 ? ei[e] : ei[2 * e];
}
__device__ __forceinline__ int ld_dst(const int* ei, int e, int is32) {
    return is32 ? ei[NE + e] : ei[2 * NE + 2 * e];
}
__device__ __forceinline__ int ld_batch(const int* b, int n, int is32) {
    return is32 ? b[n] : b[2 * n];
}
__device__ __forceinline__ float bf2f(unsigned short u) {
    return __uint_as_float(((unsigned int)u) << 16);
}
__device__ __forceinline__ int pad8(int d) { return (d + 7) & ~7; }

// ---------------- degree (int) ----------------
__global__ __launch_bounds__(256) void deg_kernel(const int* __restrict__ ei,
                                                  const int* __restrict__ flags,
                                                  int* __restrict__ deg_cnt) {
    int is32 = flags[0];
    int e = blockIdx.x * 256 + threadIdx.x;
    if (e < NE) atomicAdd(&deg_cnt[ld_dst(ei, e, is32)], 1);
}

// ---------------- scan phase 1: per-block PADDED-degree totals (+ fused dinv) ----------------
__global__ __launch_bounds__(256) void scan_part_kernel(const int* __restrict__ deg_cnt,
                                                        int* __restrict__ blocksum,
                                                        float* __restrict__ dinv) {
    __shared__ int s[256];
    int base = blockIdx.x * 1024 + threadIdx.x * 4;
    int t = 0;
    if (base < NN) {  // NN % 4 == 0 -> whole int4 in-bounds
        int4 v = *(const int4*)(deg_cnt + base);
        t = pad8(v.x) + pad8(v.y) + pad8(v.z) + pad8(v.w);
        float4 dv = make_float4(rsqrtf((float)v.x + 1.f), rsqrtf((float)v.y + 1.f),
                                rsqrtf((float)v.z + 1.f), rsqrtf((float)v.w + 1.f));
        *(float4*)(dinv + base) = dv;  // +1 self-loop
    }
    s[threadIdx.x] = t;
    __syncthreads();
    for (int off = 128; off > 0; off >>= 1) {
        if (threadIdx.x < off) s[threadIdx.x] += s[threadIdx.x + off];
        __syncthreads();
    }
    if (threadIdx.x == 0) blocksum[blockIdx.x] = s[0];
}

// ---------------- scan phase 2: re-scan block sums + write rowptr (padded) ----------------
__global__ __launch_bounds__(256) void scan_write_kernel(int* __restrict__ deg_cnt,
                                                         const int* __restrict__ blocksum,
                                                         int* __restrict__ rowptr) {
    __shared__ int sb[128];
    __shared__ int s[256];
    if (threadIdx.x < 128)
        sb[threadIdx.x] = (threadIdx.x < SCAN_BLK) ? blocksum[threadIdx.x] : 0;
    __syncthreads();
    for (int off = 1; off < 128; off <<= 1) {
        int a = 0;
        if (threadIdx.x < 128 && threadIdx.x >= off) a = sb[threadIdx.x - off];
        __syncthreads();
        if (threadIdx.x < 128) sb[threadIdx.x] += a;
        __syncthreads();
    }
    int blockpre = (blockIdx.x == 0) ? 0 : sb[blockIdx.x - 1];
    if (blockIdx.x == SCAN_BLK - 1 && threadIdx.x == 0)
        rowptr[NN] = sb[SCAN_BLK - 1];  // padded total

    int base = blockIdx.x * 1024 + threadIdx.x * 4;
    int4 v = make_int4(0, 0, 0, 0);
    if (base < NN) v = *(const int4*)(deg_cnt + base);
    int p0 = pad8(v.x), p1 = pad8(v.y), p2 = pad8(v.z), p3 = pad8(v.w);
    int t = p0 + p1 + p2 + p3;
    s[threadIdx.x] = t;
    for (int off = 1; off < 256; off <<= 1) {
        __syncthreads();
        int a = (threadIdx.x >= off) ? s[threadIdx.x - off] : 0;
        __syncthreads();
        s[threadIdx.x] += a;
    }
    __syncthreads();
    int pre = blockpre + s[threadIdx.x] - t;  // exclusive padded prefix
    if (base < NN) {
        rowptr[base] = pre;
        rowptr[base + 1] = pre + p0;
        rowptr[base + 2] = pre + p0 + p1;
        rowptr[base + 3] = pre + p0 + p1 + p2;
        *(int4*)(deg_cnt + base) = make_int4(0, 0, 0, 0);
    }
}

// ---------------- CSR fill: (byte offset | block-local dst id, weight) ----------------
__global__ __launch_bounds__(256) void fill_kernel(const int* __restrict__ ei,
                                                   const int* __restrict__ flags,
                                                   const float* __restrict__ dinv,
                                                   const int* __restrict__ rowptr,
                                                   int* __restrict__ cursor,
                                                   int2* __restrict__ csw) {
    int is32 = flags[0];
    int e = blockIdx.x * 256 + threadIdx.x;
    if (e >= NE) return;
    int s = ld_src(ei, e, is32), d = ld_dst(ei, e, is32);
    int pos = rowptr[d] + atomicAdd(&cursor[d], 1);
    float w = dinv[s] * dinv[d];
    int nl = d % GB_NODES;  // block-local node id (blocks start at multiples of 49)
    csw[pos] = make_int2((s << 7) | nl, __float_as_int(w));  // s*128 | nl (nl < 64)
}

// ---------------- LDS-tiled gemm: t_bf16 = act(BN(h)) @ W; BN stats inline ----------------
__global__ __launch_bounds__(256) void gemm_kernel(const float* __restrict__ h,
                                                   const float* __restrict__ W,
                                                   const float* __restrict__ accum_prev,
                                                   const float* __restrict__ gamma,
                                                   const float* __restrict__ beta,
                                                   int use_bn, float alpha,
                                                   bf16* __restrict__ t,
                                                   float* __restrict__ accum_l) {
    if (blockIdx.x == 0 && threadIdx.x < 128) accum_l[threadIdx.x] = 0.f;

    __shared__ float ls[TILE_ROWS * DD];  // 16 KB staged tile (post-activation)
    __shared__ float ssc[DD], ssh[DD];
    if (threadIdx.x < 64) {
        if (use_bn) {
            float S = accum_prev[threadIdx.x], Q = accum_prev[64 + threadIdx.x];
            float mean = S / (float)NN;
            float var = fmaxf(Q / (float)NN - mean * mean, 0.f);
            float sc = gamma[threadIdx.x] * rsqrtf(var + BN_EPS);
            ssc[threadIdx.x] = sc;
            ssh[threadIdx.x] = beta[threadIdx.x] - mean * sc;
        } else {
            ssc[threadIdx.x] = 1.f;
            ssh[threadIdx.x] = 0.f;
        }
    }

    int c = threadIdx.x & 63;
    int wv = threadIdx.x >> 6;  // wave id 0..3
    float w[DD];
#pragma unroll
    for (int k = 0; k < DD; ++k) w[k] = W[k * DD + c];
    __syncthreads();  // ssc/ssh ready

    for (int tile = blockIdx.x; tile < NT; tile += gridDim.x) {
        int row0 = tile * TILE_ROWS;
#pragma unroll
        for (int it = 0; it < 4; ++it) {
            int flat = (threadIdx.x + it * 256) * 4;  // 0..16380
            int gflat = row0 * DD + flat;
            if (gflat < NN * DD) {
                float4 hv = *(const float4*)(h + gflat);
                int c0 = flat & 63;
                float4 s4 = *(const float4*)(ssc + c0);
                float4 b4 = *(const float4*)(ssh + c0);
                float x0 = hv.x * s4.x + b4.x;
                float x1 = hv.y * s4.y + b4.y;
                float x2 = hv.z * s4.z + b4.z;
                float x3 = hv.w * s4.w + b4.w;
                x0 = fmaxf(x0, x0 * alpha);
                x1 = fmaxf(x1, x1 * alpha);
                x2 = fmaxf(x2, x2 * alpha);
                x3 = fmaxf(x3, x3 * alpha);
                *(float4*)(ls + flat) = make_float4(x0, x1, x2, x3);
            }
        }
        __syncthreads();
        int nrows = min(TILE_ROWS, NN - row0);
        int rend = min(wv * 16 + 16, nrows);
        for (int rl = wv * 16; rl < rend; ++rl) {
            const float4* hrow = (const float4*)(ls + rl * DD);
            float acc = 0.f;
#pragma unroll
            for (int kk = 0; kk < DD / 4; ++kk) {
                float4 hv = hrow[kk];  // wave-uniform LDS read -> broadcast
                acc += hv.x * w[4 * kk] + hv.y * w[4 * kk + 1] +
                       hv.z * w[4 * kk + 2] + hv.w * w[4 * kk + 3];
            }
            t[(size_t)(row0 + rl) * DD + c] = __float2bfloat16(acc);
        }
        __syncthreads();
    }
}

// ---------------- gather v7: edge-parallel streaming, LDS accumulation ----------------
// Waves stream the block's padded edge slice in batches of 8 with no per-node
// serialization: 8 LDS edge reads -> 8 global row loads -> 8 LDS float atomics
// into spart[nl*64+f] (bank = f%32 -> free 2-way). Pad edges add 0 to node 0.
__global__ __launch_bounds__(256) void gather_kernel(const bf16* __restrict__ t,
                                                     const float* __restrict__ dinv,
                                                     const float* __restrict__ bias,
                                                     const int* __restrict__ rowptr,
                                                     const int2* __restrict__ csw,
                                                     float* __restrict__ h,
                                                     float* __restrict__ accum_l) {
    __shared__ int2 se[ECAP];                 // 10 KB staged (offset|nl, weight)
    __shared__ float spart[GB_NODES * DD];    // 12.5 KB accumulation tile
    __shared__ int srp[GB_NODES + 1];
    __shared__ float s_sum[256], s_sq[256];

    int f = threadIdx.x & 63;
    int wv = threadIdx.x >> 6;
    int nb0 = blockIdx.x * GB_NODES;
    int nloc = min(GB_NODES, NN - nb0);

    for (int i = threadIdx.x; i <= nloc; i += 256) srp[i] = rowptr[nb0 + i];
    for (int i = threadIdx.x; i < GB_NODES * DD; i += 256) spart[i] = 0.f;
    __syncthreads();
    int ebase = srp[0];
    int nE = srp[nloc] - ebase;  // multiple of 8 (padded CSR)
    bool staged = (nE <= ECAP);
    int ncap = min(nE, ECAP);
    for (int i = threadIdx.x; i < ncap; i += 256) se[i] = csw[ebase + i];
    __syncthreads();

    const char* tbase = (const char*)t;
    int f2 = f * 2;
    const int2* ep = staged ? se : (csw + ebase);

    for (int e = wv * 8; e < nE; e += 32) {  // nE % 8 == 0 -> exact batches
        int2 a[8];
        unsigned short r[8];
#pragma unroll
        for (int u = 0; u < 8; ++u) a[u] = ep[e + u];
#pragma unroll
        for (int u = 0; u < 8; ++u)
            r[u] = *(const unsigned short*)(tbase + (unsigned)((a[u].x & ~127) + f2));
#pragma unroll
        for (int u = 0; u < 8; ++u)
            atomicAdd(&spart[(a[u].x & 127) * DD + f],
                      bf2f(r[u]) * __int_as_float(a[u].y));
    }
    __syncthreads();

    // epilogue: self + bias, write h, BN partial sums
    const unsigned short* tf = (const unsigned short*)t + f;
    float bb = bias[f];
    float sum = 0.f, sq = 0.f;
    for (int nl = wv; nl < nloc; nl += 4) {
        int d = nb0 + nl;
        float di = dinv[d];
        float acc = spart[nl * DD + f] + bf2f(tf[(size_t)d * DD]) * di * di + bb;
        h[(size_t)d * DD + f] = acc;
        sum += acc;
        sq += acc * acc;
    }
    s_sum[threadIdx.x] = sum;
    s_sq[threadIdx.x] = sq;
    __syncthreads();
    if (threadIdx.x < 64) {
        sum = s_sum[f] + s_sum[64 + f] + s_sum[128 + f] + s_sum[192 + f];
        sq = s_sq[f] + s_sq[64 + f] + s_sq[128 + f] + s_sq[192 + f];
        atomicAdd(&accum_l[f], sum);
        atomicAdd(&accum_l[64 + f], sq);
    }
}

// ---------------- pool: inline BN finalize(layer3) + ReLU + mean-pool + counts ----------------
#define POOL_CHUNK 128
__global__ __launch_bounds__(256) void pool_kernel(const float* __restrict__ hraw,
                                                   const float* __restrict__ accum_l,
                                                   const float* __restrict__ gamma,
                                                   const float* __restrict__ beta,
                                                   const int* __restrict__ batch,
                                                   const int* __restrict__ flags,
                                                   float* __restrict__ pool,
                                                   float* __restrict__ counts) {
    __shared__ float ssc[64], ssh[64];
    if (threadIdx.x < 64) {
        float S = accum_l[threadIdx.x], Q = accum_l[64 + threadIdx.x];
        float mean = S / (float)NN;
        float var = fmaxf(Q / (float)NN - mean * mean, 0.f);
        float sc = gamma[threadIdx.x] * rsqrtf(var + BN_EPS);
        ssc[threadIdx.x] = sc;
        ssh[threadIdx.x] = beta[threadIdx.x] - mean * sc;
    }
    __syncthreads();
    int is32 = flags[1];
    int f = threadIdx.x & 63, rg = threadIdx.x >> 6;
    float sc = ssc[f], sh = ssh[f];
    int base = blockIdx.x * POOL_CHUNK;
    float acc = 0.f, cnt = 0.f;
    int cur = -1;
    for (int i = rg; i < POOL_CHUNK; i += 4) {
        int n = base + i;
        if (n >= NN) break;
        int g = ld_batch(batch, n, is32);
        if (g != cur) {
            if (cur >= 0) {
                atomicAdd(&pool[cur * DD + f], acc);
                if (f == 0) atomicAdd(&counts[cur], cnt);
            }
            acc = 0.f;
            cnt = 0.f;
            cur = g;
        }
        acc += fmaxf(hraw[(size_t)n * DD + f] * sc + sh, 0.f);
        cnt += 1.f;
    }
    if (cur >= 0) {
        atomicAdd(&pool[cur * DD + f], acc);
        if (f == 0) atomicAdd(&counts[cur], cnt);
    }
}

__global__ __launch_bounds__(256) void final_kernel(const float* __restrict__ pool,
                                                    const float* __restrict__ counts,
                                                    float* __restrict__ out) {
    int i = blockIdx.x * 256 + threadIdx.x;
    if (i < NG * DD) {
        int g = i >> 6;
        out[i] = pool[i] / fmaxf(counts[g], 1.0f);
    }
}

extern "C" void kernel_launch(void* const* d_in, const int* in_sizes, int n_in,
                              void* d_out, int out_size, void* d_ws, size_t ws_size,
                              hipStream_t stream) {
    const float* x = (const float*)d_in[0];       // [NN, DD] f32
    const int* edge_index = (const int*)d_in[1];  // [2, NE] int (width detected)
    const int* batch = (const int*)d_in[2];       // [NN] int (width detected)
    const float* Ws = (const float*)d_in[3];      // [3,64,64]
    const float* bs = (const float*)d_in[4];      // [3,64]
    const float* gammas = (const float*)d_in[5];  // [3,64]
    const float* betas = (const float*)d_in[6];   // [3,64]
    float* out = (float*)d_out;                   // [NG, DD]

    // workspace layout (deg_cnt/pool/counts contiguous -> single memset)
    float* h = (float*)d_ws;                    // 6,400,000 f
    bf16* t = (bf16*)(h + (size_t)NN * DD);     // 6,400,000 bf16 (12.8 MB)
    int2* csw = (int2*)(t + (size_t)NN * DD);   // CSW_CAP int2 (18.4 MB, padded CSR)
    float* dinv = (float*)(csw + CSW_CAP);      // 100,000 f
    int* deg_cnt = (int*)(dinv + NN);           // 100,000 i (also fill cursor)
    float* pool = (float*)(deg_cnt + NN);       // 8192 f
    float* counts = pool + NG * DD;             // 128 f
    int* rowptr = (int*)(counts + NG);          // 100,001 i (padded CSR offsets)
    float* accum = (float*)(rowptr + NN + 1);   // NL*128 f (BN sum/sumsq per layer)
    int* flags = (int*)(accum + NL * 128);      // 2 i
    int* blocksum = flags + 2;                  // 128 i

    // one memset: deg_cnt + pool + counts; one for padded csw (pad slots -> w=0)
    hipMemsetAsync(deg_cnt, 0, (NN + NG * DD + NG) * sizeof(float), stream);
    hipMemsetAsync(csw, 0, (size_t)CSW_CAP * sizeof(int2), stream);

    detect_kernel<<<1, 256, 0, stream>>>(edge_index, batch, flags);
    deg_kernel<<<(NE + 255) / 256, 256, 0, stream>>>(edge_index, flags, deg_cnt);
    scan_part_kernel<<<SCAN_BLK, 256, 0, stream>>>(deg_cnt, blocksum, dinv);
    scan_write_kernel<<<SCAN_BLK, 256, 0, stream>>>(deg_cnt, blocksum, rowptr);
    fill_kernel<<<(NE + 255) / 256, 256, 0, stream>>>(edge_index, flags, dinv, rowptr,
                                                      deg_cnt, csw);

    for (int l = 0; l < NL; ++l) {
        const float* hin = (l == 0) ? x : h;
        float alpha = (l == 0) ? 1.0f : 0.0f;  // identity vs ReLU on input transform
        gemm_kernel<<<NT, 256, 0, stream>>>(hin, Ws + (size_t)l * DD * DD,
                                            accum + (l - 1 >= 0 ? l - 1 : 0) * 128,
                                            gammas + (l - 1 >= 0 ? l - 1 : 0) * DD,
                                            betas + (l - 1 >= 0 ? l - 1 : 0) * DD,
                                            (l > 0) ? 1 : 0, alpha, t, accum + l * 128);
        gather_kernel<<<GB_BLOCKS, 256, 0, stream>>>(t, dinv, bs + l * DD, rowptr, csw, h,
                                                     accum + l * 128);
    }

    pool_kernel<<<(NN + POOL_CHUNK - 1) / POOL_CHUNK, 256, 0, stream>>>(
        h, accum + 2 * 128, gammas + 2 * DD, betas + 2 * DD, batch, flags, pool, counts);
    final_kernel<<<(NG * DD + 255) / 256, 256, 0, stream>>>(pool, counts, out);
}

// Round 16
// 2327.240 us; speedup vs baseline: 1.0052x; 1.0052x over previous
//
#include <hip/hip_runtime.h>
#include <hip/hip_bf16.h>

typedef __hip_bfloat16 bf16;

#define NN 100000
#define NE 1600000
#define DD 64
#define NL 3
#define NG 128
#define BN_EPS 1e-5f
#define SCAN_BLK 98  // ceil(NN / 1024)
#define TILE_ROWS 64
#define NT ((NN + TILE_ROWS - 1) / TILE_ROWS)  // 1563
#define GB_NODES 49
#define GB_BLOCKS ((NN + GB_NODES - 1) / GB_NODES)  // 2041
#define ECAP 1280    // staged padded edges per block (mean ~955, sd ~28)
#define CSW_CAP (NE + 7 * NN)  // padded CSR worst case

// ---------------- dtype detect (int64 vs int32) ----------------
__global__ __launch_bounds__(256) void detect_kernel(const int* __restrict__ ei,
                                                     const int* __restrict__ batch,
                                                     int* __restrict__ flags) {
    __shared__ int s_e, s_b;
    if (threadIdx.x == 0) { s_e = 0; s_b = 0; }
    __syncthreads();
    for (int i = threadIdx.x; i < 512; i += 256) {
        if (ei[2 * i + 1] != 0) atomicOr(&s_e, 1);
        if (batch[NN - 1024 + 2 * i + 1] != 0) atomicOr(&s_b, 1);
    }
    __syncthreads();
    if (threadIdx.x == 0) { flags[0] = s_e; flags[1] = s_b; }  // 1 = int32, 0 = int64
}

__device__ __forceinline__ int ld_src(const int* ei, int e, int is32) {
    return is32 ? ei[e] : ei[2 * e];
}
__device__ __forceinline__ int ld_dst(const int* ei, int e, int is32) {
    return is32 ? ei[NE + e] : ei[2 * NE + 2 * e];
}
__device__ __forceinline__ int ld_batch(const int* b, int n, int is32) {
    return is32 ? b[n] : b[2 * n];
}
__device__ __forceinline__ float bf2f(unsigned short u) {
    return __uint_as_float(((unsigned int)u) << 16);
}
__device__ __forceinline__ int pad8(int d) { return (d + 7) & ~7; }

// ---------------- degree (int) ----------------
__global__ __launch_bounds__(256) void deg_kernel(const int* __restrict__ ei,
                                                  const int* __restrict__ flags,
                                                  int* __restrict__ deg_cnt) {
    int is32 = flags[0];
    int e = blockIdx.x * 256 + threadIdx.x;
    if (e < NE) atomicAdd(&deg_cnt[ld_dst(ei, e, is32)], 1);
}

// ---------------- scan phase 1: per-block PADDED-degree totals (+ fused dinv) ----------------
__global__ __launch_bounds__(256) void scan_part_kernel(const int* __restrict__ deg_cnt,
                                                        int* __restrict__ blocksum,
                                                        float* __restrict__ dinv) {
    __shared__ int s[256];
    int base = blockIdx.x * 1024 + threadIdx.x * 4;
    int t = 0;
    if (base < NN) {  // NN % 4 == 0 -> whole int4 in-bounds
        int4 v = *(const int4*)(deg_cnt + base);
        t = pad8(v.x) + pad8(v.y) + pad8(v.z) + pad8(v.w);
        float4 dv = make_float4(rsqrtf((float)v.x + 1.f), rsqrtf((float)v.y + 1.f),
                                rsqrtf((float)v.z + 1.f), rsqrtf((float)v.w + 1.f));
        *(float4*)(dinv + base) = dv;  // +1 self-loop
    }
    s[threadIdx.x] = t;
    __syncthreads();
    for (int off = 128; off > 0; off >>= 1) {
        if (threadIdx.x < off) s[threadIdx.x] += s[threadIdx.x + off];
        __syncthreads();
    }
    if (threadIdx.x == 0) blocksum[blockIdx.x] = s[0];
}

// ---------------- scan phase 2: re-scan block sums + write rowptr (padded) ----------------
__global__ __launch_bounds__(256) void scan_write_kernel(int* __restrict__ deg_cnt,
                                                         const int* __restrict__ blocksum,
                                                         int* __restrict__ rowptr) {
    __shared__ int sb[128];
    __shared__ int s[256];
    if (threadIdx.x < 128)
        sb[threadIdx.x] = (threadIdx.x < SCAN_BLK) ? blocksum[threadIdx.x] : 0;
    __syncthreads();
    for (int off = 1; off < 128; off <<= 1) {
        int a = 0;
        if (threadIdx.x < 128 && threadIdx.x >= off) a = sb[threadIdx.x - off];
        __syncthreads();
        if (threadIdx.x < 128) sb[threadIdx.x] += a;
        __syncthreads();
    }
    int blockpre = (blockIdx.x == 0) ? 0 : sb[blockIdx.x - 1];
    if (blockIdx.x == SCAN_BLK - 1 && threadIdx.x == 0)
        rowptr[NN] = sb[SCAN_BLK - 1];  // padded total

    int base = blockIdx.x * 1024 + threadIdx.x * 4;
    int4 v = make_int4(0, 0, 0, 0);
    if (base < NN) v = *(const int4*)(deg_cnt + base);
    int p0 = pad8(v.x), p1 = pad8(v.y), p2 = pad8(v.z), p3 = pad8(v.w);
    int t = p0 + p1 + p2 + p3;
    s[threadIdx.x] = t;
    for (int off = 1; off < 256; off <<= 1) {
        __syncthreads();
        int a = (threadIdx.x >= off) ? s[threadIdx.x - off] : 0;
        __syncthreads();
        s[threadIdx.x] += a;
    }
    __syncthreads();
    int pre = blockpre + s[threadIdx.x] - t;  // exclusive padded prefix
    if (base < NN) {
        rowptr[base] = pre;
        rowptr[base + 1] = pre + p0;
        rowptr[base + 2] = pre + p0 + p1;
        rowptr[base + 3] = pre + p0 + p1 + p2;
        *(int4*)(deg_cnt + base) = make_int4(0, 0, 0, 0);
    }
}

// ---------------- CSR fill: (byte offset | block-local dst id, weight) ----------------
__global__ __launch_bounds__(256) void fill_kernel(const int* __restrict__ ei,
                                                   const int* __restrict__ flags,
                                                   const float* __restrict__ dinv,
                                                   const int* __restrict__ rowptr,
                                                   int* __restrict__ cursor,
                                                   int2* __restrict__ csw) {
    int is32 = flags[0];
    int e = blockIdx.x * 256 + threadIdx.x;
    if (e >= NE) return;
    int s = ld_src(ei, e, is32), d = ld_dst(ei, e, is32);
    int pos = rowptr[d] + atomicAdd(&cursor[d], 1);
    float w = dinv[s] * dinv[d];
    int nl = d % GB_NODES;  // block-local node id (blocks start at multiples of 49)
    csw[pos] = make_int2((s << 7) | nl, __float_as_int(w));  // s*128 | nl (nl < 128)
}

// ---------------- LDS-tiled gemm: t_bf16 = act(BN(h)) @ W; BN stats inline ----------------
__global__ __launch_bounds__(256) void gemm_kernel(const float* __restrict__ h,
                                                   const float* __restrict__ W,
                                                   const float* __restrict__ accum_prev,
                                                   const float* __restrict__ gamma,
                                                   const float* __restrict__ beta,
                                                   int use_bn, float alpha,
                                                   bf16* __restrict__ t,
                                                   float* __restrict__ accum_l) {
    if (blockIdx.x == 0 && threadIdx.x < 128) accum_l[threadIdx.x] = 0.f;

    __shared__ float ls[TILE_ROWS * DD];  // 16 KB staged tile (post-activation)
    __shared__ float ssc[DD], ssh[DD];
    if (threadIdx.x < 64) {
        if (use_bn) {
            float S = accum_prev[threadIdx.x], Q = accum_prev[64 + threadIdx.x];
            float mean = S / (float)NN;
            float var = fmaxf(Q / (float)NN - mean * mean, 0.f);
            float sc = gamma[threadIdx.x] * rsqrtf(var + BN_EPS);
            ssc[threadIdx.x] = sc;
            ssh[threadIdx.x] = beta[threadIdx.x] - mean * sc;
        } else {
            ssc[threadIdx.x] = 1.f;
            ssh[threadIdx.x] = 0.f;
        }
    }

    int c = threadIdx.x & 63;
    int wv = threadIdx.x >> 6;  // wave id 0..3
    float w[DD];
#pragma unroll
    for (int k = 0; k < DD; ++k) w[k] = W[k * DD + c];
    __syncthreads();  // ssc/ssh ready

    for (int tile = blockIdx.x; tile < NT; tile += gridDim.x) {
        int row0 = tile * TILE_ROWS;
#pragma unroll
        for (int it = 0; it < 4; ++it) {
            int flat = (threadIdx.x + it * 256) * 4;  // 0..16380
            int gflat = row0 * DD + flat;
            if (gflat < NN * DD) {
                float4 hv = *(const float4*)(h + gflat);
                int c0 = flat & 63;
                float4 s4 = *(const float4*)(ssc + c0);
                float4 b4 = *(const float4*)(ssh + c0);
                float x0 = hv.x * s4.x + b4.x;
                float x1 = hv.y * s4.y + b4.y;
                float x2 = hv.z * s4.z + b4.z;
                float x3 = hv.w * s4.w + b4.w;
                x0 = fmaxf(x0, x0 * alpha);
                x1 = fmaxf(x1, x1 * alpha);
                x2 = fmaxf(x2, x2 * alpha);
                x3 = fmaxf(x3, x3 * alpha);
                *(float4*)(ls + flat) = make_float4(x0, x1, x2, x3);
            }
        }
        __syncthreads();
        int nrows = min(TILE_ROWS, NN - row0);
        int rend = min(wv * 16 + 16, nrows);
        for (int rl = wv * 16; rl < rend; ++rl) {
            const float4* hrow = (const float4*)(ls + rl * DD);
            float acc = 0.f;
#pragma unroll
            for (int kk = 0; kk < DD / 4; ++kk) {
                float4 hv = hrow[kk];  // wave-uniform LDS read -> broadcast
                acc += hv.x * w[4 * kk] + hv.y * w[4 * kk + 1] +
                       hv.z * w[4 * kk + 2] + hv.w * w[4 * kk + 3];
            }
            t[(size_t)(row0 + rl) * DD + c] = __float2bfloat16(acc);
        }
        __syncthreads();
    }
}

// ---------------- gather v8: edge-parallel + LDS accumulate, EXPLICIT address spaces ----------------
// v7's bug: `staged ? se : csw` pointer-select forced flat addressing (LDS via
// flat_load = slow generic path). v8 keeps the two paths in separate branches so
// the staged path emits ds_read_b64 (wave-uniform broadcast) and the overflow
// path emits global_load. 8-edge batches; ds_add_f32 into spart (bank = f%32,
// 2-way = free). Pad edges add 0*row[0] to node 0: harmless.
__global__ __launch_bounds__(256) void gather_kernel(const bf16* __restrict__ t,
                                                     const float* __restrict__ dinv,
                                                     const float* __restrict__ bias,
                                                     const int* __restrict__ rowptr,
                                                     const int2* __restrict__ csw,
                                                     float* __restrict__ h,
                                                     float* __restrict__ accum_l) {
    __shared__ int2 se[ECAP];               // 10 KB staged (offset|nl, weight)
    __shared__ float spart[GB_NODES * DD];  // 12.25 KB accumulation tile
    __shared__ float s_sum[256], s_sq[256];
    __shared__ int s_bounds[2];

    int f = threadIdx.x & 63;
    int wv = threadIdx.x >> 6;
    int nb0 = blockIdx.x * GB_NODES;
    int nloc = min(GB_NODES, NN - nb0);

    if (threadIdx.x == 0) {
        s_bounds[0] = rowptr[nb0];
        s_bounds[1] = rowptr[nb0 + nloc];
    }
    for (int i = threadIdx.x; i < GB_NODES * DD; i += 256) spart[i] = 0.f;
    __syncthreads();
    int ebase = s_bounds[0];
    int nE = s_bounds[1] - ebase;  // multiple of 8 (padded CSR)
    bool staged = (nE <= ECAP);
    int ncap = min(nE, ECAP);
    for (int i = threadIdx.x; i < ncap; i += 256) se[i] = csw[ebase + i];
    __syncthreads();

    const char* tbase = (const char*)t;
    int f2 = f * 2;

    if (staged) {
        for (int e = wv * 8; e < nE; e += 32) {  // nE % 8 == 0 -> exact batches
            int2 a[8];
            unsigned short r[8];
#pragma unroll
            for (int u = 0; u < 8; ++u) a[u] = se[e + u];  // LDS broadcast
#pragma unroll
            for (int u = 0; u < 8; ++u)
                r[u] = *(const unsigned short*)(tbase + (unsigned)((a[u].x & ~127) + f2));
#pragma unroll
            for (int u = 0; u < 8; ++u)
                atomicAdd(&spart[(a[u].x & 127) * DD + f],
                          bf2f(r[u]) * __int_as_float(a[u].y));
        }
    } else {  // overflow block (vanishingly rare): edges from global
        for (int e = wv * 8; e < nE; e += 32) {
            int2 a[8];
            unsigned short r[8];
#pragma unroll
            for (int u = 0; u < 8; ++u) a[u] = csw[ebase + e + u];
#pragma unroll
            for (int u = 0; u < 8; ++u)
                r[u] = *(const unsigned short*)(tbase + (unsigned)((a[u].x & ~127) + f2));
#pragma unroll
            for (int u = 0; u < 8; ++u)
                atomicAdd(&spart[(a[u].x & 127) * DD + f],
                          bf2f(r[u]) * __int_as_float(a[u].y));
        }
    }
    __syncthreads();

    // epilogue: self + bias, write h, BN partial sums
    const unsigned short* tf = (const unsigned short*)t + f;
    float bb = bias[f];
    float sum = 0.f, sq = 0.f;
    for (int nl = wv; nl < nloc; nl += 4) {
        int d = nb0 + nl;
        float di = dinv[d];
        float acc = spart[nl * DD + f] + bf2f(tf[(size_t)d * DD]) * di * di + bb;
        h[(size_t)d * DD + f] = acc;
        sum += acc;
        sq += acc * acc;
    }
    s_sum[threadIdx.x] = sum;
    s_sq[threadIdx.x] = sq;
    __syncthreads();
    if (threadIdx.x < 64) {
        sum = s_sum[f] + s_sum[64 + f] + s_sum[128 + f] + s_sum[192 + f];
        sq = s_sq[f] + s_sq[64 + f] + s_sq[128 + f] + s_sq[192 + f];
        atomicAdd(&accum_l[f], sum);
        atomicAdd(&accum_l[64 + f], sq);
    }
}

// ---------------- pool: inline BN finalize(layer3) + ReLU + mean-pool + counts ----------------
#define POOL_CHUNK 128
__global__ __launch_bounds__(256) void pool_kernel(const float* __restrict__ hraw,
                                                   const float* __restrict__ accum_l,
                                                   const float* __restrict__ gamma,
                                                   const float* __restrict__ beta,
                                                   const int* __restrict__ batch,
                                                   const int* __restrict__ flags,
                                                   float* __restrict__ pool,
                                                   float* __restrict__ counts) {
    __shared__ float ssc[64], ssh[64];
    if (threadIdx.x < 64) {
        float S = accum_l[threadIdx.x], Q = accum_l[64 + threadIdx.x];
        float mean = S / (float)NN;
        float var = fmaxf(Q / (float)NN - mean * mean, 0.f);
        float sc = gamma[threadIdx.x] * rsqrtf(var + BN_EPS);
        ssc[threadIdx.x] = sc;
        ssh[threadIdx.x] = beta[threadIdx.x] - mean * sc;
    }
    __syncthreads();
    int is32 = flags[1];
    int f = threadIdx.x & 63, rg = threadIdx.x >> 6;
    float sc = ssc[f], sh = ssh[f];
    int base = blockIdx.x * POOL_CHUNK;
    float acc = 0.f, cnt = 0.f;
    int cur = -1;
    for (int i = rg; i < POOL_CHUNK; i += 4) {
        int n = base + i;
        if (n >= NN) break;
        int g = ld_batch(batch, n, is32);
        if (g != cur) {
            if (cur >= 0) {
                atomicAdd(&pool[cur * DD + f], acc);
                if (f == 0) atomicAdd(&counts[cur], cnt);
            }
            acc = 0.f;
            cnt = 0.f;
            cur = g;
        }
        acc += fmaxf(hraw[(size_t)n * DD + f] * sc + sh, 0.f);
        cnt += 1.f;
    }
    if (cur >= 0) {
        atomicAdd(&pool[cur * DD + f], acc);
        if (f == 0) atomicAdd(&counts[cur], cnt);
    }
}

__global__ __launch_bounds__(256) void final_kernel(const float* __restrict__ pool,
                                                    const float* __restrict__ counts,
                                                    float* __restrict__ out) {
    int i = blockIdx.x * 256 + threadIdx.x;
    if (i < NG * DD) {
        int g = i >> 6;
        out[i] = pool[i] / fmaxf(counts[g], 1.0f);
    }
}

extern "C" void kernel_launch(void* const* d_in, const int* in_sizes, int n_in,
                              void* d_out, int out_size, void* d_ws, size_t ws_size,
                              hipStream_t stream) {
    const float* x = (const float*)d_in[0];       // [NN, DD] f32
    const int* edge_index = (const int*)d_in[1];  // [2, NE] int (width detected)
    const int* batch = (const int*)d_in[2];       // [NN] int (width detected)
    const float* Ws = (const float*)d_in[3];      // [3,64,64]
    const float* bs = (const float*)d_in[4];      // [3,64]
    const float* gammas = (const float*)d_in[5];  // [3,64]
    const float* betas = (const float*)d_in[6];   // [3,64]
    float* out = (float*)d_out;                   // [NG, DD]

    // workspace layout (deg_cnt/pool/counts contiguous -> single memset)
    float* h = (float*)d_ws;                    // 6,400,000 f
    bf16* t = (bf16*)(h + (size_t)NN * DD);     // 6,400,000 bf16 (12.8 MB)
    int2* csw = (int2*)(t + (size_t)NN * DD);   // CSW_CAP int2 (18.4 MB, padded CSR)
    float* dinv = (float*)(csw + CSW_CAP);      // 100,000 f
    int* deg_cnt = (int*)(dinv + NN);           // 100,000 i (also fill cursor)
    float* pool = (float*)(deg_cnt + NN);       // 8192 f
    float* counts = pool + NG * DD;             // 128 f
    int* rowptr = (int*)(counts + NG);          // 100,001 i (padded CSR offsets)
    float* accum = (float*)(rowptr + NN + 1);   // NL*128 f (BN sum/sumsq per layer)
    int* flags = (int*)(accum + NL * 128);      // 2 i
    int* blocksum = flags + 2;                  // 128 i

    // one memset: deg_cnt + pool + counts; one for padded csw (pad slots -> w=0)
    hipMemsetAsync(deg_cnt, 0, (NN + NG * DD + NG) * sizeof(float), stream);
    hipMemsetAsync(csw, 0, (size_t)CSW_CAP * sizeof(int2), stream);

    detect_kernel<<<1, 256, 0, stream>>>(edge_index, batch, flags);
    deg_kernel<<<(NE + 255) / 256, 256, 0, stream>>>(edge_index, flags, deg_cnt);
    scan_part_kernel<<<SCAN_BLK, 256, 0, stream>>>(deg_cnt, blocksum, dinv);
    scan_write_kernel<<<SCAN_BLK, 256, 0, stream>>>(deg_cnt, blocksum, rowptr);
    fill_kernel<<<(NE + 255) / 256, 256, 0, stream>>>(edge_index, flags, dinv, rowptr,
                                                      deg_cnt, csw);

    for (int l = 0; l < NL; ++l) {
        const float* hin = (l == 0) ? x : h;
        float alpha = (l == 0) ? 1.0f : 0.0f;  // identity vs ReLU on input transform
        gemm_kernel<<<NT, 256, 0, stream>>>(hin, Ws + (size_t)l * DD * DD,
                                            accum + (l - 1 >= 0 ? l - 1 : 0) * 128,
                                            gammas + (l - 1 >= 0 ? l - 1 : 0) * DD,
                                            betas + (l - 1 >= 0 ? l - 1 : 0) * DD,
                                            (l > 0) ? 1 : 0, alpha, t, accum + l * 128);
        gather_kernel<<<GB_BLOCKS, 256, 0, stream>>>(t, dinv, bs + l * DD, rowptr, csw, h,
                                                     accum + l * 128);
    }

    pool_kernel<<<(NN + POOL_CHUNK - 1) / POOL_CHUNK, 256, 0, stream>>>(
        h, accum + 2 * 128, gammas + 2 * DD, betas + 2 * DD, batch, flags, pool, counts);
    final_kernel<<<(NG * DD + 255) / 256, 256, 0, stream>>>(pool, counts, out);
}

// Round 17
// 649.594 us; speedup vs baseline: 3.6014x; 3.5826x over previous
//
#include <hip/hip_runtime.h>
#include <hip/hip_bf16.h>

typedef __hip_bfloat16 bf16;

#define NN 100000
#define NE 1600000
#define DD 64
#define NL 3
#define NG 128
#define BN_EPS 1e-5f
#define SCAN_BLK 98  // ceil(NN / 1024)
#define TILE_ROWS 64
#define NT ((NN + TILE_ROWS - 1) / TILE_ROWS)  // 1563
#define GB_NODES 49
#define GB_BLOCKS ((NN + GB_NODES - 1) / GB_NODES)  // 2041
#define ECAP 1664    // staged padded edges per block (mean ~955)
#define CSW_CAP (NE + 7 * NN)  // padded CSR worst case

// ---------------- dtype detect (int64 vs int32) ----------------
__global__ __launch_bounds__(256) void detect_kernel(const int* __restrict__ ei,
                                                     const int* __restrict__ batch,
                                                     int* __restrict__ flags) {
    __shared__ int s_e, s_b;
    if (threadIdx.x == 0) { s_e = 0; s_b = 0; }
    __syncthreads();
    for (int i = threadIdx.x; i < 512; i += 256) {
        if (ei[2 * i + 1] != 0) atomicOr(&s_e, 1);
        if (batch[NN - 1024 + 2 * i + 1] != 0) atomicOr(&s_b, 1);
    }
    __syncthreads();
    if (threadIdx.x == 0) { flags[0] = s_e; flags[1] = s_b; }  // 1 = int32, 0 = int64
}

__device__ __forceinline__ int ld_src(const int* ei, int e, int is32) {
    return is32 ? ei[e] : ei[2 * e];
}
__device__ __forceinline__ int ld_dst(const int* ei, int e, int is32) {
    return is32 ? ei[NE + e] : ei[2 * NE + 2 * e];
}
__device__ __forceinline__ int ld_batch(const int* b, int n, int is32) {
    return is32 ? b[n] : b[2 * n];
}
__device__ __forceinline__ float bf2f(unsigned short u) {
    return __uint_as_float(((unsigned int)u) << 16);
}
__device__ __forceinline__ int pad8(int d) { return (d + 7) & ~7; }

// ---------------- degree (int) ----------------
__global__ __launch_bounds__(256) void deg_kernel(const int* __restrict__ ei,
                                                  const int* __restrict__ flags,
                                                  int* __restrict__ deg_cnt) {
    int is32 = flags[0];
    int e = blockIdx.x * 256 + threadIdx.x;
    if (e < NE) atomicAdd(&deg_cnt[ld_dst(ei, e, is32)], 1);
}

// ---------------- scan phase 1: per-block PADDED-degree totals (+ fused dinv) ----------------
__global__ __launch_bounds__(256) void scan_part_kernel(const int* __restrict__ deg_cnt,
                                                        int* __restrict__ blocksum,
                                                        float* __restrict__ dinv) {
    __shared__ int s[256];
    int base = blockIdx.x * 1024 + threadIdx.x * 4;
    int t = 0;
    if (base < NN) {  // NN % 4 == 0 -> whole int4 in-bounds
        int4 v = *(const int4*)(deg_cnt + base);
        t = pad8(v.x) + pad8(v.y) + pad8(v.z) + pad8(v.w);
        float4 dv = make_float4(rsqrtf((float)v.x + 1.f), rsqrtf((float)v.y + 1.f),
                                rsqrtf((float)v.z + 1.f), rsqrtf((float)v.w + 1.f));
        *(float4*)(dinv + base) = dv;  // +1 self-loop
    }
    s[threadIdx.x] = t;
    __syncthreads();
    for (int off = 128; off > 0; off >>= 1) {
        if (threadIdx.x < off) s[threadIdx.x] += s[threadIdx.x + off];
        __syncthreads();
    }
    if (threadIdx.x == 0) blocksum[blockIdx.x] = s[0];
}

// ---------------- scan phase 2: re-scan block sums + write rowptr (padded) ----------------
__global__ __launch_bounds__(256) void scan_write_kernel(int* __restrict__ deg_cnt,
                                                         const int* __restrict__ blocksum,
                                                         int* __restrict__ rowptr) {
    __shared__ int sb[128];
    __shared__ int s[256];
    if (threadIdx.x < 128)
        sb[threadIdx.x] = (threadIdx.x < SCAN_BLK) ? blocksum[threadIdx.x] : 0;
    __syncthreads();
    for (int off = 1; off < 128; off <<= 1) {
        int a = 0;
        if (threadIdx.x < 128 && threadIdx.x >= off) a = sb[threadIdx.x - off];
        __syncthreads();
        if (threadIdx.x < 128) sb[threadIdx.x] += a;
        __syncthreads();
    }
    int blockpre = (blockIdx.x == 0) ? 0 : sb[blockIdx.x - 1];
    if (blockIdx.x == SCAN_BLK - 1 && threadIdx.x == 0)
        rowptr[NN] = sb[SCAN_BLK - 1];  // padded total

    int base = blockIdx.x * 1024 + threadIdx.x * 4;
    int4 v = make_int4(0, 0, 0, 0);
    if (base < NN) v = *(const int4*)(deg_cnt + base);
    int p0 = pad8(v.x), p1 = pad8(v.y), p2 = pad8(v.z), p3 = pad8(v.w);
    int t = p0 + p1 + p2 + p3;
    s[threadIdx.x] = t;
    for (int off = 1; off < 256; off <<= 1) {
        __syncthreads();
        int a = (threadIdx.x >= off) ? s[threadIdx.x - off] : 0;
        __syncthreads();
        s[threadIdx.x] += a;
    }
    __syncthreads();
    int pre = blockpre + s[threadIdx.x] - t;  // exclusive padded prefix
    if (base < NN) {
        rowptr[base] = pre;
        rowptr[base + 1] = pre + p0;
        rowptr[base + 2] = pre + p0 + p1;
        rowptr[base + 3] = pre + p0 + p1 + p2;
        *(int4*)(deg_cnt + base) = make_int4(0, 0, 0, 0);
    }
}

// ---------------- CSR fill: (pre-scaled byte offset, weight); pads stay zero ----------------
__global__ __launch_bounds__(256) void fill_kernel(const int* __restrict__ ei,
                                                   const int* __restrict__ flags,
                                                   const float* __restrict__ dinv,
                                                   const int* __restrict__ rowptr,
                                                   int* __restrict__ cursor,
                                                   int2* __restrict__ csw) {
    int is32 = flags[0];
    int e = blockIdx.x * 256 + threadIdx.x;
    if (e >= NE) return;
    int s = ld_src(ei, e, is32), d = ld_dst(ei, e, is32);
    int pos = rowptr[d] + atomicAdd(&cursor[d], 1);
    float w = dinv[s] * dinv[d];
    csw[pos] = make_int2(s << 7, __float_as_int(w));  // s * DD * sizeof(bf16) = s*128
}

// ---------------- LDS-tiled gemm: t_bf16 = act(BN(h)) @ W; BN stats inline ----------------
__global__ __launch_bounds__(256) void gemm_kernel(const float* __restrict__ h,
                                                   const float* __restrict__ W,
                                                   const float* __restrict__ accum_prev,
                                                   const float* __restrict__ gamma,
                                                   const float* __restrict__ beta,
                                                   int use_bn, float alpha,
                                                   bf16* __restrict__ t,
                                                   float* __restrict__ accum_l) {
    if (blockIdx.x == 0 && threadIdx.x < 128) accum_l[threadIdx.x] = 0.f;

    __shared__ float ls[TILE_ROWS * DD];  // 16 KB staged tile (post-activation)
    __shared__ float ssc[DD], ssh[DD];
    if (threadIdx.x < 64) {
        if (use_bn) {
            float S = accum_prev[threadIdx.x], Q = accum_prev[64 + threadIdx.x];
            float mean = S / (float)NN;
            float var = fmaxf(Q / (float)NN - mean * mean, 0.f);
            float sc = gamma[threadIdx.x] * rsqrtf(var + BN_EPS);
            ssc[threadIdx.x] = sc;
            ssh[threadIdx.x] = beta[threadIdx.x] - mean * sc;
        } else {
            ssc[threadIdx.x] = 1.f;
            ssh[threadIdx.x] = 0.f;
        }
    }

    int c = threadIdx.x & 63;
    int wv = threadIdx.x >> 6;  // wave id 0..3
    float w[DD];
#pragma unroll
    for (int k = 0; k < DD; ++k) w[k] = W[k * DD + c];
    __syncthreads();  // ssc/ssh ready

    for (int tile = blockIdx.x; tile < NT; tile += gridDim.x) {
        int row0 = tile * TILE_ROWS;
#pragma unroll
        for (int it = 0; it < 4; ++it) {
            int flat = (threadIdx.x + it * 256) * 4;  // 0..16380
            int gflat = row0 * DD + flat;
            if (gflat < NN * DD) {
                float4 hv = *(const float4*)(h + gflat);
                int c0 = flat & 63;
                float4 s4 = *(const float4*)(ssc + c0);
                float4 b4 = *(const float4*)(ssh + c0);
                float x0 = hv.x * s4.x + b4.x;
                float x1 = hv.y * s4.y + b4.y;
                float x2 = hv.z * s4.z + b4.z;
                float x3 = hv.w * s4.w + b4.w;
                x0 = fmaxf(x0, x0 * alpha);
                x1 = fmaxf(x1, x1 * alpha);
                x2 = fmaxf(x2, x2 * alpha);
                x3 = fmaxf(x3, x3 * alpha);
                *(float4*)(ls + flat) = make_float4(x0, x1, x2, x3);
            }
        }
        __syncthreads();
        int nrows = min(TILE_ROWS, NN - row0);
        int rend = min(wv * 16 + 16, nrows);
        for (int rl = wv * 16; rl < rend; ++rl) {
            const float4* hrow = (const float4*)(ls + rl * DD);
            float acc = 0.f;
#pragma unroll
            for (int kk = 0; kk < DD / 4; ++kk) {
                float4 hv = hrow[kk];  // wave-uniform LDS read -> broadcast
                acc += hv.x * w[4 * kk] + hv.y * w[4 * kk + 1] +
                       hv.z * w[4 * kk + 2] + hv.w * w[4 * kk + 3];
            }
            t[(size_t)(row0 + rl) * DD + c] = __float2bfloat16(acc);
        }
        __syncthreads();
    }
}

// ---------------- gather v9: r14 structure + 16-deep dual-node windows ----------------
__device__ __forceinline__ void batch8(const int2* __restrict__ ep, int j,
                                       const char* __restrict__ tbase, int f2,
                                       float& acc) {
    int2 a[8];
    unsigned short r[8];
#pragma unroll
    for (int u = 0; u < 8; ++u) a[u] = ep[j + u];
#pragma unroll
    for (int u = 0; u < 8; ++u)
        r[u] = *(const unsigned short*)(tbase + (unsigned)(a[u].x + f2));
#pragma unroll
    for (int u = 0; u < 8; ++u) acc += bf2f(r[u]) * __int_as_float(a[u].y);
}

__device__ __forceinline__ void batch8x2(const int2* __restrict__ ep, int jA, int jB,
                                         const char* __restrict__ tbase, int f2,
                                         float& accA, float& accB) {
    int2 aA[8], aB[8];
    unsigned short rA[8], rB[8];
#pragma unroll
    for (int u = 0; u < 8; ++u) { aA[u] = ep[jA + u]; aB[u] = ep[jB + u]; }
#pragma unroll
    for (int u = 0; u < 8; ++u) {
        rA[u] = *(const unsigned short*)(tbase + (unsigned)(aA[u].x + f2));
        rB[u] = *(const unsigned short*)(tbase + (unsigned)(aB[u].x + f2));
    }
#pragma unroll
    for (int u = 0; u < 8; ++u) {
        accA += bf2f(rA[u]) * __int_as_float(aA[u].y);
        accB += bf2f(rB[u]) * __int_as_float(aB[u].y);
    }
}

__device__ __forceinline__ void batch16x2(const int2* __restrict__ ep, int jA, int jB,
                                          const char* __restrict__ tbase, int f2,
                                          float& accA, float& accB) {
    int2 aA[16], aB[16];
    unsigned short rA[16], rB[16];
#pragma unroll
    for (int u = 0; u < 16; ++u) { aA[u] = ep[jA + u]; aB[u] = ep[jB + u]; }
#pragma unroll
    for (int u = 0; u < 16; ++u) {
        rA[u] = *(const unsigned short*)(tbase + (unsigned)(aA[u].x + f2));
        rB[u] = *(const unsigned short*)(tbase + (unsigned)(aB[u].x + f2));
    }
#pragma unroll
    for (int u = 0; u < 16; ++u) {
        accA += bf2f(rA[u]) * __int_as_float(aA[u].y);
        accB += bf2f(rB[u]) * __int_as_float(aB[u].y);
    }
}

__global__ __launch_bounds__(256) void gather_kernel(const bf16* __restrict__ t,
                                                     const float* __restrict__ dinv,
                                                     const float* __restrict__ bias,
                                                     const int* __restrict__ rowptr,
                                                     const int2* __restrict__ csw,
                                                     float* __restrict__ h,
                                                     float* __restrict__ accum_l) {
    __shared__ int2 se[ECAP];          // 13 KB staged (byte-offset, weight)
    __shared__ int srp[GB_NODES + 1];  // staged rowptr slice
    __shared__ float s_sum[256], s_sq[256];

    int f = threadIdx.x & 63;
    int wv = threadIdx.x >> 6;
    int nb0 = blockIdx.x * GB_NODES;
    int nloc = min(GB_NODES, NN - nb0);

    for (int i = threadIdx.x; i <= nloc; i += 256) srp[i] = rowptr[nb0 + i];
    __syncthreads();
    int ebase = srp[0];
    int nE = srp[nloc] - ebase;
    bool staged = (nE <= ECAP);
    int ncap = min(nE, ECAP);
    for (int i = threadIdx.x; i < ncap; i += 256) se[i] = csw[ebase + i];
    __syncthreads();

    const char* tbase = (const char*)t;
    int f2 = f * 2;
    const unsigned short* tf = (const unsigned short*)t + f;
    float bb = bias[f];
    float sum = 0.f, sq = 0.f;

    for (int p = wv; 2 * p < nloc; p += 4) {  // wave handles node pair (2p, 2p+1)
        int dlA = 2 * p, dlB = dlA + 1;
        int dA = nb0 + dlA;
        bool hasB = dlB < nloc;
        int dB = hasB ? nb0 + dlB : dA;
        float diA = dinv[dA], diB = dinv[dB];
        float accA = bf2f(tf[(size_t)dA * DD]) * diA * diA + bb;
        float accB = hasB ? (bf2f(tf[(size_t)dB * DD]) * diB * diB + bb) : 0.f;
        int jA = srp[dlA] - ebase, jendA = srp[dlA + 1] - ebase;  // multiples of 8
        int jB = jendA, jendB = hasB ? (srp[dlB + 1] - ebase) : jendA;

        if (staged) {
            for (; jA + 16 <= jendA && jB + 16 <= jendB; jA += 16, jB += 16)
                batch16x2(se, jA, jB, tbase, f2, accA, accB);
            for (; jA < jendA && jB < jendB; jA += 8, jB += 8)
                batch8x2(se, jA, jB, tbase, f2, accA, accB);
            for (; jA < jendA; jA += 8) batch8(se, jA, tbase, f2, accA);
            for (; jB < jendB; jB += 8) batch8(se, jB, tbase, f2, accB);
        } else {  // overflow block (vanishingly rare): csw from global
            const int2* ep = csw + ebase;
            for (; jA + 16 <= jendA && jB + 16 <= jendB; jA += 16, jB += 16)
                batch16x2(ep, jA, jB, tbase, f2, accA, accB);
            for (; jA < jendA && jB < jendB; jA += 8, jB += 8)
                batch8x2(ep, jA, jB, tbase, f2, accA, accB);
            for (; jA < jendA; jA += 8) batch8(ep, jA, tbase, f2, accA);
            for (; jB < jendB; jB += 8) batch8(ep, jB, tbase, f2, accB);
        }
        h[(size_t)dA * DD + f] = accA;
        sum += accA;
        sq += accA * accA;
        if (hasB) {
            h[(size_t)dB * DD + f] = accB;
            sum += accB;
            sq += accB * accB;
        }
    }
    s_sum[threadIdx.x] = sum;
    s_sq[threadIdx.x] = sq;
    __syncthreads();
    if (threadIdx.x < 64) {
        sum = s_sum[f] + s_sum[64 + f] + s_sum[128 + f] + s_sum[192 + f];
        sq = s_sq[f] + s_sq[64 + f] + s_sq[128 + f] + s_sq[192 + f];
        atomicAdd(&accum_l[f], sum);
        atomicAdd(&accum_l[64 + f], sq);
    }
}

// ---------------- pool: inline BN finalize(layer3) + ReLU + mean-pool + counts ----------------
#define POOL_CHUNK 128
__global__ __launch_bounds__(256) void pool_kernel(const float* __restrict__ hraw,
                                                   const float* __restrict__ accum_l,
                                                   const float* __restrict__ gamma,
                                                   const float* __restrict__ beta,
                                                   const int* __restrict__ batch,
                                                   const int* __restrict__ flags,
                                                   float* __restrict__ pool,
                                                   float* __restrict__ counts) {
    __shared__ float ssc[64], ssh[64];
    if (threadIdx.x < 64) {
        float S = accum_l[threadIdx.x], Q = accum_l[64 + threadIdx.x];
        float mean = S / (float)NN;
        float var = fmaxf(Q / (float)NN - mean * mean, 0.f);
        float sc = gamma[threadIdx.x] * rsqrtf(var + BN_EPS);
        ssc[threadIdx.x] = sc;
        ssh[threadIdx.x] = beta[threadIdx.x] - mean * sc;
    }
    __syncthreads();
    int is32 = flags[1];
    int f = threadIdx.x & 63, rg = threadIdx.x >> 6;
    float sc = ssc[f], sh = ssh[f];
    int base = blockIdx.x * POOL_CHUNK;
    float acc = 0.f, cnt = 0.f;
    int cur = -1;
    for (int i = rg; i < POOL_CHUNK; i += 4) {
        int n = base + i;
        if (n >= NN) break;
        int g = ld_batch(batch, n, is32);
        if (g != cur) {
            if (cur >= 0) {
                atomicAdd(&pool[cur * DD + f], acc);
                if (f == 0) atomicAdd(&counts[cur], cnt);
            }
            acc = 0.f;
            cnt = 0.f;
            cur = g;
        }
        acc += fmaxf(hraw[(size_t)n * DD + f] * sc + sh, 0.f);
        cnt += 1.f;
    }
    if (cur >= 0) {
        atomicAdd(&pool[cur * DD + f], acc);
        if (f == 0) atomicAdd(&counts[cur], cnt);
    }
}

__global__ __launch_bounds__(256) void final_kernel(const float* __restrict__ pool,
                                                    const float* __restrict__ counts,
                                                    float* __restrict__ out) {
    int i = blockIdx.x * 256 + threadIdx.x;
    if (i < NG * DD) {
        int g = i >> 6;
        out[i] = pool[i] / fmaxf(counts[g], 1.0f);
    }
}

extern "C" void kernel_launch(void* const* d_in, const int* in_sizes, int n_in,
                              void* d_out, int out_size, void* d_ws, size_t ws_size,
                              hipStream_t stream) {
    const float* x = (const float*)d_in[0];       // [NN, DD] f32
    const int* edge_index = (const int*)d_in[1];  // [2, NE] int (width detected)
    const int* batch = (const int*)d_in[2];       // [NN] int (width detected)
    const float* Ws = (const float*)d_in[3];      // [3,64,64]
    const float* bs = (const float*)d_in[4];      // [3,64]
    const float* gammas = (const float*)d_in[5];  // [3,64]
    const float* betas = (const float*)d_in[6];   // [3,64]
    float* out = (float*)d_out;                   // [NG, DD]

    // workspace layout (deg_cnt/pool/counts contiguous -> single memset)
    float* h = (float*)d_ws;                    // 6,400,000 f
    bf16* t = (bf16*)(h + (size_t)NN * DD);     // 6,400,000 bf16 (12.8 MB)
    int2* csw = (int2*)(t + (size_t)NN * DD);   // CSW_CAP int2 (18.4 MB, padded CSR)
    float* dinv = (float*)(csw + CSW_CAP);      // 100,000 f
    int* deg_cnt = (int*)(dinv + NN);           // 100,000 i (also fill cursor)
    float* pool = (float*)(deg_cnt + NN);       // 8192 f
    float* counts = pool + NG * DD;             // 128 f
    int* rowptr = (int*)(counts + NG);          // 100,001 i (padded CSR offsets)
    float* accum = (float*)(rowptr + NN + 1);   // NL*128 f (BN sum/sumsq per layer)
    int* flags = (int*)(accum + NL * 128);      // 2 i
    int* blocksum = flags + 2;                  // 128 i

    // one memset: deg_cnt + pool + counts; one for padded csw (pad slots -> w=0)
    hipMemsetAsync(deg_cnt, 0, (NN + NG * DD + NG) * sizeof(float), stream);
    hipMemsetAsync(csw, 0, (size_t)CSW_CAP * sizeof(int2), stream);

    detect_kernel<<<1, 256, 0, stream>>>(edge_index, batch, flags);
    deg_kernel<<<(NE + 255) / 256, 256, 0, stream>>>(edge_index, flags, deg_cnt);
    scan_part_kernel<<<SCAN_BLK, 256, 0, stream>>>(deg_cnt, blocksum, dinv);
    scan_write_kernel<<<SCAN_BLK, 256, 0, stream>>>(deg_cnt, blocksum, rowptr);
    fill_kernel<<<(NE + 255) / 256, 256, 0, stream>>>(edge_index, flags, dinv, rowptr,
                                                      deg_cnt, csw);

    for (int l = 0; l < NL; ++l) {
        const float* hin = (l == 0) ? x : h;
        float alpha = (l == 0) ? 1.0f : 0.0f;  // identity vs ReLU on input transform
        gemm_kernel<<<NT, 256, 0, stream>>>(hin, Ws + (size_t)l * DD * DD,
                                            accum + (l - 1 >= 0 ? l - 1 : 0) * 128,
                                            gammas + (l - 1 >= 0 ? l - 1 : 0) * DD,
                                            betas + (l - 1 >= 0 ? l - 1 : 0) * DD,
                                            (l > 0) ? 1 : 0, alpha, t, accum + l * 128);
        gather_kernel<<<GB_BLOCKS, 256, 0, stream>>>(t, dinv, bs + l * DD, rowptr, csw, h,
                                                     accum + l * 128);
    }

    pool_kernel<<<(NN + POOL_CHUNK - 1) / POOL_CHUNK, 256, 0, stream>>>(
        h, accum + 2 * 128, gammas + 2 * DD, betas + 2 * DD, batch, flags, pool, counts);
    final_kernel<<<(NG * DD + 255) / 256, 256, 0, stream>>>(pool, counts, out);
}